// Round 1
// baseline (218.604 us; speedup 1.0000x reference)
//
#include <hip/hip_runtime.h>

// y[b, c, h, w] = x[b, h, w] * kernels[c, h, w]
// B=128, C=32, H=W=224 -> HW = 50176 floats = 12544 float4 per (b,c) slab.
// Pure HBM-write-bound broadcasted multiply. 822 MB out, 32 MB in.

#define HW   50176
#define HW4  12544   // HW / 4
#define CC   32

__global__ __launch_bounds__(256) void involution_mul_kernel(
    const float* __restrict__ x,
    const float* __restrict__ k,
    float* __restrict__ out)
{
    const int bc = blockIdx.y;           // b*C + c, 0..4095
    const int b  = bc >> 5;              // / 32
    const int c  = bc & 31;              // % 32
    const int i  = blockIdx.x * 256 + threadIdx.x;  // float4 idx in [0, 12544)
    // 49 blocks * 256 threads == 12544 exactly: no bounds check needed.

    const float4 xv = reinterpret_cast<const float4*>(x + (size_t)b * HW)[i];
    const float4 kv = reinterpret_cast<const float4*>(k + (size_t)c * HW)[i];
    float4 o;
    o.x = xv.x * kv.x;
    o.y = xv.y * kv.y;
    o.z = xv.z * kv.z;
    o.w = xv.w * kv.w;
    reinterpret_cast<float4*>(out + (size_t)bc * HW)[i] = o;
}

extern "C" void kernel_launch(void* const* d_in, const int* in_sizes, int n_in,
                              void* d_out, int out_size, void* d_ws, size_t ws_size,
                              hipStream_t stream) {
    const float* x = (const float*)d_in[0];   // [128, 224, 224]
    const float* k = (const float*)d_in[1];   // [32, 224, 224]
    float* out = (float*)d_out;               // [128, 32, 224, 224]

    dim3 grid(HW4 / 256, 128 * CC);           // (49, 4096)
    involution_mul_kernel<<<grid, 256, 0, stream>>>(x, k, out);
}

// Round 3
// 149.076 us; speedup vs baseline: 1.4664x; 1.4664x over previous
//
#include <hip/hip_runtime.h>

// y[b, c, h, w] = x[b, h, w] * kernels[c, h, w]
// B=128, C=32, H=W=224 -> HW = 50176 floats = 12544 float4 per slab.
// HBM-write-bound (822 MB out, 32 MB in). Register-tile 4b x 4c per thread
// to cut L2/L3 read pressure 4x; nontemporal stores keep L2 clean for reads.

#define HW    50176
#define HW4   12544          // HW / 4 (float4 units)
#define CC    32
#define BB    128
#define NB    4              // b's per thread
#define NC    4              // c's per thread

typedef float f32x4 __attribute__((ext_vector_type(4)));

__global__ __launch_bounds__(256) void involution_mul_kernel(
    const float* __restrict__ x,
    const float* __restrict__ k,
    float* __restrict__ out)
{
    const int i  = blockIdx.x * 256 + threadIdx.x;   // float4 idx in [0, HW4)
    const int ty = blockIdx.y;                       // tile id: 32 b-tiles * 8 c-tiles
    const int b0 = (ty >> 3) * NB;                   // b tile base
    const int c0 = (ty & 7) * NC;                    // c tile base

    const f32x4* xp = reinterpret_cast<const f32x4*>(x) + (size_t)b0 * HW4 + i;
    const f32x4* kp = reinterpret_cast<const f32x4*>(k) + (size_t)c0 * HW4 + i;

    f32x4 xv[NB], kv[NC];
#pragma unroll
    for (int ib = 0; ib < NB; ++ib) xv[ib] = xp[(size_t)ib * HW4];
#pragma unroll
    for (int ic = 0; ic < NC; ++ic) kv[ic] = kp[(size_t)ic * HW4];

    f32x4* op = reinterpret_cast<f32x4*>(out) + ((size_t)b0 * CC + c0) * HW4 + i;
#pragma unroll
    for (int ib = 0; ib < NB; ++ib) {
#pragma unroll
        for (int ic = 0; ic < NC; ++ic) {
            f32x4 o = xv[ib] * kv[ic];
            __builtin_nontemporal_store(o, op + ((size_t)ib * CC + ic) * HW4);
        }
    }
}

extern "C" void kernel_launch(void* const* d_in, const int* in_sizes, int n_in,
                              void* d_out, int out_size, void* d_ws, size_t ws_size,
                              hipStream_t stream) {
    const float* x = (const float*)d_in[0];   // [128, 224, 224]
    const float* k = (const float*)d_in[1];   // [32, 224, 224]
    float* out = (float*)d_out;               // [128, 32, 224, 224]

    dim3 grid(HW4 / 256, (BB / NB) * (CC / NC));   // (49, 256)
    involution_mul_kernel<<<grid, 256, 0, stream>>>(x, k, out);
}